// Round 2
// baseline (257.238 us; speedup 1.0000x reference)
//
#include <hip/hip_runtime.h>
#include <math.h>

namespace {

constexpr int kB  = 2;
constexpr int kN  = 192;
constexpr int kC  = 32;
constexpr int kH  = 64;
constexpr int kNB = 20;
constexpr int kLayers = 2;

// G[z,b,h,i] = sum_j W2[h, i*C + j] * feat[z,b,j]
__global__ __launch_bounds__(256) void g_kernel(
    const float* __restrict__ feat,   // [B*N, C]
    const float* __restrict__ W2,     // [H, C*C]
    float* __restrict__ G)            // [B*N, H*C]
{
    __shared__ float fsh[kC];
    const int zb  = blockIdx.x;
    const int tid = threadIdx.x;
    if (tid < kC) fsh[tid] = feat[zb * kC + tid];
    __syncthreads();
#pragma unroll
    for (int r = 0; r < (kH * kC) / 256; ++r) {
        const int idx = tid + 256 * r;                 // idx = h*32 + i
        const float* w = W2 + (idx >> 5) * (kC * kC) + (idx & 31) * kC;
        float s = 0.f;
#pragma unroll
        for (int j = 0; j < kC; ++j) s = fmaf(w[j], fsh[j], s);
        G[zb * (kH * kC) + idx] = s;
    }
}

// S[z,j] = sum_b feat[z,b,j]
__global__ void s_kernel(const float* __restrict__ feat, float* __restrict__ S)
{
    const int z = blockIdx.x;
    const int j = threadIdx.x;
    if (j < kC) {
        float s = 0.f;
        for (int b = 0; b < kN; ++b) s += feat[(z * kN + b) * kC + j];
        S[z * kC + j] = s;
    }
}

// One block per (z,a). 8 waves; wave w owns b in [w*24, w*24+24), 2 edges/iter.
__global__ __launch_bounds__(512) void conv_kernel(
    const float* __restrict__ xyz,    // [B,N,3]
    const float* __restrict__ mask,   // [B,N]
    const float* __restrict__ W0,     // [NB,H]
    const float* __restrict__ b0,     // [H]
    const float* __restrict__ W1,     // [H,H]
    const float* __restrict__ b1,     // [H]
    const float* __restrict__ b2,     // [C*C]
    const float* __restrict__ G,      // [B*N, H*C]
    const float* __restrict__ S,      // [B,C]
    float* __restrict__ out)          // [B,N,C]
{
    __shared__ float rb_sh[kN][kNB];   // 15360 B
    __shared__ float h1_sh[8][2][kH];  //  4096 B
    __shared__ float red_sh[8][kC];    //  1024 B

    const int tid  = threadIdx.x;
    const int wave = tid >> 6;
    const int lane = tid & 63;
    const int z = blockIdx.x / kN;
    const int a = blockIdx.x - z * kN;

    const float ax = xyz[(z * kN + a) * 3 + 0];
    const float ay = xyz[(z * kN + a) * 3 + 1];
    const float az = xyz[(z * kN + a) * 3 + 2];

    constexpr float kStep    = 10.0f / 19.0f;
    constexpr float kInvStep = 19.0f / 10.0f;
    if (tid < kN) {
        const int b = tid;
        const float dx = xyz[(z * kN + b) * 3 + 0] - ax;
        const float dy = xyz[(z * kN + b) * 3 + 1] - ay;
        const float dz = xyz[(z * kN + b) * 3 + 2] - az;
        const float d  = sqrtf(fmaf(dx, dx, fmaf(dy, dy, fmaf(dz, dz, 1e-12f))));
#pragma unroll
        for (int k = 0; k < kNB; ++k) {
            float y = (d - kStep * (float)k) * kInvStep;
            y = fminf(1.f, fmaxf(-1.f, y));
            rb_sh[b][k] = __cosf(1.57079632679f * y);
        }
    }

    // Per-lane weight columns (h = lane)
    float w0c[kNB];
#pragma unroll
    for (int k = 0; k < kNB; ++k) w0c[k] = W0[k * kH + lane];
    float w1c[kH];
#pragma unroll
    for (int k = 0; k < kH; ++k) w1c[k] = W1[k * kH + lane];
    const float b0v = b0[lane];
    const float b1v = b1[lane];

    float acc[kC];
#pragma unroll
    for (int i = 0; i < kC; ++i) acc[i] = 0.f;

    __syncthreads();   // rb_sh ready (cross-wave)

    const int bbase = wave * 24;
    for (int j = 0; j < 12; ++j) {
        const int bA = bbase + j;
        const int bB = bbase + 12 + j;

        // h1 for both edges (2 interleaved FMA chains)
        float sA = b0v, sB = b0v;
#pragma unroll
        for (int k = 0; k < kNB; ++k) {
            sA = fmaf(rb_sh[bA][k], w0c[k], sA);
            sB = fmaf(rb_sh[bB][k], w0c[k], sB);
        }
        h1_sh[wave][0][lane] = fmaxf(sA, 0.f);
        h1_sh[wave][1][lane] = fmaxf(sB, 0.f);
        __builtin_amdgcn_wave_barrier();   // wave-internal LDS ordering

        // h2 for both edges (4 interleaved chains)
        float tA0 = b1v, tA1 = 0.f, tB0 = b1v, tB1 = 0.f;
#pragma unroll
        for (int k = 0; k < kH / 2; ++k) {
            tA0 = fmaf(h1_sh[wave][0][k],      w1c[k],      tA0);
            tA1 = fmaf(h1_sh[wave][0][k + 32], w1c[k + 32], tA1);
            tB0 = fmaf(h1_sh[wave][1][k],      w1c[k],      tB0);
            tB1 = fmaf(h1_sh[wave][1][k + 32], w1c[k + 32], tB1);
        }
        const float h2A = fmaxf(tA0 + tA1, 0.f);
        const float h2B = fmaxf(tB0 + tB1, 0.f);

        // acc[i] += h2A*G[z,bA,lane,i] + h2B*G[z,bB,lane,i]
        const float4* gA = reinterpret_cast<const float4*>(
            G + ((size_t)(z * kN + bA) * kH + lane) * kC);
        const float4* gB = reinterpret_cast<const float4*>(
            G + ((size_t)(z * kN + bB) * kH + lane) * kC);
#pragma unroll
        for (int q = 0; q < 8; ++q) {
            const float4 vA = gA[q];
            const float4 vB = gB[q];
            acc[4 * q + 0] = fmaf(h2A, vA.x, fmaf(h2B, vB.x, acc[4 * q + 0]));
            acc[4 * q + 1] = fmaf(h2A, vA.y, fmaf(h2B, vB.y, acc[4 * q + 1]));
            acc[4 * q + 2] = fmaf(h2A, vA.z, fmaf(h2B, vB.z, acc[4 * q + 2]));
            acc[4 * q + 3] = fmaf(h2A, vA.w, fmaf(h2B, vB.w, acc[4 * q + 3]));
        }
        __builtin_amdgcn_wave_barrier();
    }

    // Reduce acc over 64 lanes (butterfly), then over 8 waves via LDS
#pragma unroll
    for (int i = 0; i < kC; ++i) {
        float v = acc[i];
#pragma unroll
        for (int off = 32; off > 0; off >>= 1) v += __shfl_xor(v, off, 64);
        acc[i] = v;
    }
    if (lane == 0) {
#pragma unroll
        for (int i = 0; i < kC; ++i) red_sh[wave][i] = acc[i];
    }
    __syncthreads();
    if (tid < kC) {
        const int i = tid;
        float v = 0.f;
#pragma unroll
        for (int w = 0; w < 8; ++w) v += red_sh[w][i];
        float bt = 0.f;
#pragma unroll
        for (int j = 0; j < kC; ++j) bt = fmaf(b2[i * kC + j], S[z * kC + j], bt);
        constexpr float kInvSqrtN = 0.07216878364870323f;  // 1/sqrt(192)
        v = (v + bt) * kInvSqrtN * mask[z * kN + a];
        out[(z * kN + a) * kC + i] = v;
    }
}

} // namespace

extern "C" void kernel_launch(void* const* d_in, const int* in_sizes, int n_in,
                              void* d_out, int out_size, void* d_ws, size_t ws_size,
                              hipStream_t stream) {
    const float* features = (const float*)d_in[0];
    const float* xyz      = (const float*)d_in[1];
    const float* mask     = (const float*)d_in[2];
    const float* W0       = (const float*)d_in[3];
    const float* b0       = (const float*)d_in[4];
    const float* W1       = (const float*)d_in[5];
    const float* b1       = (const float*)d_in[6];
    const float* W2       = (const float*)d_in[7];
    const float* b2       = (const float*)d_in[8];
    float* out = (float*)d_out;

    char* ws = (char*)d_ws;
    float* G    = (float*)ws;                              // B*N*H*C = 786432 f
    float* S    = (float*)(ws + 786432 * 4);               // 64 f (pad to 256 B)
    float* ftmp = (float*)(ws + 786432 * 4 + 256);         // B*N*C = 12288 f

    const float* cur = features;
    for (int l = 0; l < kLayers; ++l) {
        float* dst = (l == kLayers - 1) ? out : ftmp;
        g_kernel<<<kB * kN, 256, 0, stream>>>(cur, W2 + (size_t)l * kH * kC * kC, G);
        s_kernel<<<kB, 64, 0, stream>>>(cur, S);
        conv_kernel<<<kB * kN, 512, 0, stream>>>(
            xyz, mask,
            W0 + (size_t)l * kNB * kH, b0 + (size_t)l * kH,
            W1 + (size_t)l * kH * kH,  b1 + (size_t)l * kH,
            b2 + (size_t)l * kC * kC,
            G, S, dst);
        cur = dst;
    }
}

// Round 3
// 181.058 us; speedup vs baseline: 1.4207x; 1.4207x over previous
//
#include <hip/hip_runtime.h>
#include <math.h>

namespace {

constexpr int kB  = 2;
constexpr int kN  = 192;
constexpr int kC  = 32;
constexpr int kH  = 64;
constexpr int kNB = 20;
constexpr int kLayers = 2;
constexpr int kK  = kN * kH;      // 12288 contraction length per z
constexpr int kKC = 128;          // K-chunk per gemm block
constexpr int kNC = kK / kKC;     // 96 chunks per z
constexpr float kInvSqrtN = 0.07216878364870323f;  // 1/sqrt(192)

// ---------------- G[z,b,h,i] = sum_j W2[h, i*C+j] * feat[z,b,j] ----------------
__global__ __launch_bounds__(256) void g_kernel(
    const float* __restrict__ feat,   // [B*N, C]
    const float* __restrict__ W2,     // [H, C*C]
    float* __restrict__ G)            // [B*N, H*C]  (K-major: K=b*64+h, then i)
{
    __shared__ float fsh[kC];
    const int zb  = blockIdx.x;
    const int tid = threadIdx.x;
    if (tid < kC) fsh[tid] = feat[zb * kC + tid];
    __syncthreads();
#pragma unroll
    for (int r = 0; r < (kH * kC) / 256; ++r) {
        const int idx = tid + 256 * r;                 // idx = h*32 + i
        const float* w = W2 + (idx >> 5) * (kC * kC) + (idx & 31) * kC;
        float s = 0.f;
#pragma unroll
        for (int j = 0; j < kC; ++j) s = fmaf(w[j], fsh[j], s);
        G[(size_t)zb * (kH * kC) + idx] = s;
    }
}

// ---------------- S[z,j] = sum_b feat[z,b,j] ----------------
__global__ __launch_bounds__(256) void s_kernel(
    const float* __restrict__ feat, float* __restrict__ S)
{
    __shared__ float red[8][kC];
    const int z = blockIdx.x;
    const int t = threadIdx.x;
    const int j = t & 31, s = t >> 5;   // 8 slices x 32 j
    float acc = 0.f;
    for (int b = s; b < kN; b += 8) acc += feat[(z * kN + b) * kC + j];
    red[s][j] = acc;
    __syncthreads();
    if (t < kC) {
        float v = 0.f;
#pragma unroll
        for (int q = 0; q < 8; ++q) v += red[q][t];
        S[z * kC + t] = v;
    }
}

// ---------------- edge kernel: one lane per edge ----------------
// h2b[z][a][b][h] (bf16)  — K-flat index (b*64+h) matches G's K-major layout.
__device__ inline unsigned int bf16pack(float lo, float hi) {
    unsigned int ul = __float_as_uint(lo), uh = __float_as_uint(hi);
    ul = (ul + 0x7FFFu + ((ul >> 16) & 1u)) >> 16;
    uh = (uh + 0x7FFFu + ((uh >> 16) & 1u)) >> 16;
    return ul | (uh << 16);
}

__global__ __launch_bounds__(256, 2) void edge_kernel(
    const float* __restrict__ xyz,    // [B,N,3]
    const float* __restrict__ W0,     // [NB,H]
    const float* __restrict__ b0,     // [H]
    const float* __restrict__ W1,     // [H,H]
    const float* __restrict__ b1,     // [H]
    unsigned short* __restrict__ h2b) // [B*N*N, H] bf16
{
    __shared__ float w0s[kNB * kH];   // 5 KB
    __shared__ float w1s[kH * kH];    // 16 KB
    __shared__ float b0s[kH], b1s[kH];

    const int tid = threadIdx.x;
    for (int t = tid; t < kNB * kH; t += 256) w0s[t] = W0[t];
    for (int t = tid; t < kH * kH; t += 256) w1s[t] = W1[t];
    if (tid < kH) { b0s[tid] = b0[tid]; b1s[tid] = b1[tid]; }
    __syncthreads();

    const int E = blockIdx.x * 256 + tid;   // < 73728
    const int z = E / (kN * kN);
    const int r = E - z * (kN * kN);
    const int a = r / kN;
    const int b = r - a * kN;

    const float ax = xyz[(z * kN + a) * 3 + 0];
    const float ay = xyz[(z * kN + a) * 3 + 1];
    const float az = xyz[(z * kN + a) * 3 + 2];
    const float dx = xyz[(z * kN + b) * 3 + 0] - ax;
    const float dy = xyz[(z * kN + b) * 3 + 1] - ay;
    const float dz = xyz[(z * kN + b) * 3 + 2] - az;
    const float d  = sqrtf(fmaf(dx, dx, fmaf(dy, dy, fmaf(dz, dz, 1e-12f))));

    constexpr float kInvStep = 19.0f / 10.0f;
    const float dn = d * kInvStep;          // y_k = clamp(dn - k, -1, 1)
    float rb[kNB];
#pragma unroll
    for (int k = 0; k < kNB; ++k) {
        float y = dn - (float)k;
        y = fminf(1.f, fmaxf(-1.f, y));
        rb[k] = __cosf(1.57079632679f * y);
    }

    // h1 = relu(rb @ W0 + b0): 64 independent accumulator chains
    float h1[kH];
#pragma unroll
    for (int h = 0; h < kH; ++h) h1[h] = b0s[h];
#pragma unroll
    for (int k = 0; k < kNB; ++k) {
        const float rk = rb[k];
#pragma unroll
        for (int h = 0; h < kH; ++h) h1[h] = fmaf(rk, w0s[k * kH + h], h1[h]);
    }
#pragma unroll
    for (int h = 0; h < kH; ++h) h1[h] = fmaxf(h1[h], 0.f);

    // h2 = relu(h1 @ W1 + b1), streamed 8 outputs at a time, stored bf16
    unsigned short* dst = h2b + (size_t)E * kH;
    for (int g = 0; g < 8; ++g) {           // runtime g keeps code size small
        float q[8];
#pragma unroll
        for (int j = 0; j < 8; ++j) q[j] = b1s[g * 8 + j];
#pragma unroll
        for (int k = 0; k < kH; ++k) {
            const float hk = h1[k];
#pragma unroll
            for (int j = 0; j < 8; ++j)
                q[j] = fmaf(hk, w1s[k * kH + g * 8 + j], q[j]);
        }
        uint4 pk;
        pk.x = bf16pack(fmaxf(q[0], 0.f), fmaxf(q[1], 0.f));
        pk.y = bf16pack(fmaxf(q[2], 0.f), fmaxf(q[3], 0.f));
        pk.z = bf16pack(fmaxf(q[4], 0.f), fmaxf(q[5], 0.f));
        pk.w = bf16pack(fmaxf(q[6], 0.f), fmaxf(q[7], 0.f));
        *reinterpret_cast<uint4*>(dst + g * 8) = pk;
    }
}

// ---------------- gemm: partial[z,c,a,i] = sum_{k in chunk c} h2[a,k] G[k,i] ----------------
__global__ __launch_bounds__(256) void gemm_kernel(
    const unsigned short* __restrict__ h2b,  // [z*N, kK] bf16 (rows a, K-major)
    const float* __restrict__ G,             // [z, kK, 32]
    float* __restrict__ partial)             // [z*kNC, kN, 32]
{
    __shared__ float Gs[kKC * kC];       // 16 KB
    __shared__ float h2s[32 * 129];      // 16.1 KB (padded rows: bank-conflict-free)

    const int tid = threadIdx.x;
    const int zc  = blockIdx.x;          // z*kNC + c
    const int z   = zc / kNC;
    const int c   = zc - z * kNC;
    const int K0  = c * kKC;

    // stage G chunk [128][32]
    const float* gsrc = G + ((size_t)z * kK + K0) * kC;
#pragma unroll
    for (int p = 0; p < 4; ++p) {
        const int idx = tid * 4 + p * 1024;
        *reinterpret_cast<float4*>(&Gs[idx]) =
            *reinterpret_cast<const float4*>(&gsrc[idx]);
    }

    const int arow = tid >> 3;           // 0..31 (row within staged tile)
    const int iq   = (tid & 7) * 4;      // 0,4,...,28

    for (int ag = 0; ag < kN / 32; ++ag) {   // 6 tiles of 32 a-rows
        __syncthreads();                      // protect h2s overwrite
        const unsigned short* hb =
            h2b + ((size_t)z * kN + ag * 32) * (size_t)kK + K0;
#pragma unroll
        for (int p = 0; p < 4; ++p) {
            const int idx = tid * 4 + p * 1024;   // 0..4095
            const int rr = idx >> 7, kk = idx & 127;
            const uint2 u = *reinterpret_cast<const uint2*>(hb + (size_t)rr * kK + kk);
            float* dd = &h2s[rr * 129 + kk];
            dd[0] = __uint_as_float(u.x << 16);
            dd[1] = __uint_as_float(u.x & 0xffff0000u);
            dd[2] = __uint_as_float(u.y << 16);
            dd[3] = __uint_as_float(u.y & 0xffff0000u);
        }
        __syncthreads();                      // h2s (and, first iter, Gs) ready

        const float* hrow = &h2s[arow * 129];
        float a0 = 0.f, a1 = 0.f, a2 = 0.f, a3 = 0.f;
#pragma unroll
        for (int k = 0; k < kKC; ++k) {
            const float hv = hrow[k];
            const float4 g4 = *reinterpret_cast<const float4*>(&Gs[k * kC + iq]);
            a0 = fmaf(hv, g4.x, a0);
            a1 = fmaf(hv, g4.y, a1);
            a2 = fmaf(hv, g4.z, a2);
            a3 = fmaf(hv, g4.w, a3);
        }
        float4 res; res.x = a0; res.y = a1; res.z = a2; res.w = a3;
        *reinterpret_cast<float4*>(
            &partial[((size_t)zc * kN + ag * 32 + arow) * kC + iq]) = res;
    }
}

// ---------------- reduce: out = (sum_c partial + b2@S) * mask / sqrt(n) ----------------
__global__ __launch_bounds__(256) void reduce_kernel(
    const float* __restrict__ partial,   // [z*kNC, kN, 32]
    const float* __restrict__ S,         // [B, C]
    const float* __restrict__ b2,        // [C*C]
    const float* __restrict__ mask,      // [B, N]
    float* __restrict__ dst)             // [B, N, C]
{
    const int o = blockIdx.x * 256 + threadIdx.x;   // < 12288
    const int z = o / (kN * kC);
    const int ai = o - z * (kN * kC);
    const int i = ai & 31, a = ai >> 5;
    const float* p = partial + (size_t)z * kNC * kN * kC + ai;
    float acc = 0.f;
#pragma unroll 8
    for (int c = 0; c < kNC; ++c) acc += p[(size_t)c * kN * kC];
    float bt = 0.f;
#pragma unroll
    for (int j = 0; j < kC; ++j) bt = fmaf(b2[i * kC + j], S[z * kC + j], bt);
    dst[o] = (acc + bt) * kInvSqrtN * mask[z * kN + a];
}

} // namespace

extern "C" void kernel_launch(void* const* d_in, const int* in_sizes, int n_in,
                              void* d_out, int out_size, void* d_ws, size_t ws_size,
                              hipStream_t stream) {
    const float* features = (const float*)d_in[0];
    const float* xyz      = (const float*)d_in[1];
    const float* mask     = (const float*)d_in[2];
    const float* W0       = (const float*)d_in[3];
    const float* b0       = (const float*)d_in[4];
    const float* W1       = (const float*)d_in[5];
    const float* b1       = (const float*)d_in[6];
    const float* W2       = (const float*)d_in[7];
    const float* b2       = (const float*)d_in[8];
    float* out = (float*)d_out;

    // workspace layout (floats):
    //   G       :       0 .. 786432          (B*N*H*C)
    //   S       :  786432 .. 786560          (pad)
    //   h2b     :  786560 .. 3145856         (73728*64 bf16 = 2359296 f)
    //   partial : 3145856 .. 4325504         (2*96*192*32)
    //   ftmp    : 4325504 .. 4337792
    float* ws = (float*)d_ws;
    float* G        = ws;
    float* S        = ws + 786432;
    unsigned short* h2b = (unsigned short*)(ws + 786560);
    float* partial  = ws + 3145856;
    float* ftmp     = ws + 4325504;

    const float* cur = features;
    for (int l = 0; l < kLayers; ++l) {
        float* dst = (l == kLayers - 1) ? out : ftmp;
        g_kernel<<<kB * kN, 256, 0, stream>>>(cur, W2 + (size_t)l * kH * kC * kC, G);
        s_kernel<<<kB, 256, 0, stream>>>(cur, S);
        edge_kernel<<<(kB * kN * kN) / 256, 256, 0, stream>>>(
            xyz,
            W0 + (size_t)l * kNB * kH, b0 + (size_t)l * kH,
            W1 + (size_t)l * kH * kH,  b1 + (size_t)l * kH,
            h2b);
        gemm_kernel<<<kB * kNC, 256, 0, stream>>>(h2b, G, partial);
        reduce_kernel<<<(kB * kN * kC) / 256, 256, 0, stream>>>(
            partial, S, b2 + (size_t)l * kC * kC, mask, dst);
        cur = dst;
    }
}

// Round 4
// 111.701 us; speedup vs baseline: 2.3029x; 1.6209x over previous
//
#include <hip/hip_runtime.h>
#include <math.h>

namespace {

constexpr int kB  = 2;
constexpr int kN  = 192;
constexpr int kC  = 32;
constexpr int kH  = 64;
constexpr int kNB = 20;
constexpr int kLayers = 2;
constexpr int kK  = kN * kH;      // 12288 contraction length per z
constexpr int kKC = 128;          // K-chunk per gemm block
constexpr int kNC = kK / kKC;     // 96 chunks per z
constexpr float kInvSqrtN = 0.07216878364870323f;  // 1/sqrt(192)

typedef __attribute__((ext_vector_type(8))) short bf16x8;
typedef __attribute__((ext_vector_type(4))) float f32x4;

__device__ inline unsigned short bf16r(float x) {   // RNE f32->bf16
    unsigned int u = __float_as_uint(x);
    u = (u + 0x7FFFu + ((u >> 16) & 1u)) >> 16;
    return (unsigned short)u;
}
__device__ inline unsigned int bf16pk(float lo, float hi) {
    return (unsigned int)bf16r(lo) | ((unsigned int)bf16r(hi) << 16);
}

// ---------------- G[z,b,h,i] = sum_j W2[h, i*C+j] * feat[z,b,j] ----------------
__global__ __launch_bounds__(256) void g_kernel(
    const float* __restrict__ feat,   // [B*N, C]
    const float* __restrict__ W2,     // [H, C*C]
    float* __restrict__ G)            // [B*N, H*C]  (K-major: K=b*64+h, then i)
{
    __shared__ float fsh[kC];
    const int zb  = blockIdx.x;
    const int tid = threadIdx.x;
    if (tid < kC) fsh[tid] = feat[zb * kC + tid];
    __syncthreads();
#pragma unroll
    for (int r = 0; r < (kH * kC) / 256; ++r) {
        const int idx = tid + 256 * r;                 // idx = h*32 + i
        const float* w = W2 + (idx >> 5) * (kC * kC) + (idx & 31) * kC;
        float s = 0.f;
#pragma unroll
        for (int j = 0; j < kC; ++j) s = fmaf(w[j], fsh[j], s);
        G[(size_t)zb * (kH * kC) + idx] = s;
    }
}

// ---------------- S[z,j] = sum_b feat[z,b,j] ----------------
__global__ __launch_bounds__(256) void s_kernel(
    const float* __restrict__ feat, float* __restrict__ S)
{
    __shared__ float red[8][kC];
    const int z = blockIdx.x;
    const int t = threadIdx.x;
    const int j = t & 31, s = t >> 5;   // 8 slices x 32 j
    float acc = 0.f;
    for (int b = s; b < kN; b += 8) acc += feat[(z * kN + b) * kC + j];
    red[s][j] = acc;
    __syncthreads();
    if (t < kC) {
        float v = 0.f;
#pragma unroll
        for (int q = 0; q < 8; ++q) v += red[q][t];
        S[z * kC + t] = v;
    }
}

// ---------------- edge kernel (MFMA): block = (z,a), 192 edges ----------------
// Consistent sigma for all K packings: frag elem i of lane-group g <-> k = 8*g + i.
// h2b[(z*N+a)*N + b][h] bf16, i.e. row a, K-major k=b*64+h.
__global__ __launch_bounds__(256) void edge_mfma_kernel(
    const float* __restrict__ xyz,    // [B,N,3]
    const float* __restrict__ W0,     // [NB,H]
    const float* __restrict__ b0,     // [H]
    const float* __restrict__ W1,     // [H,H]
    const float* __restrict__ b1,     // [H]
    unsigned short* __restrict__ h2b) // [B*N*N, H] bf16
{
    __shared__ __align__(16) unsigned short rbb[4 * kN * 8];  // [kb4][e192][8] 12KB
    __shared__ __align__(16) unsigned short h1b[8 * kN * 8];  // [kb8][e192][8] 24KB

    const int tid  = threadIdx.x;
    const int wave = tid >> 6, lane = tid & 63;
    const int g = lane >> 4, l15 = lane & 15;
    const int z = blockIdx.x / kN, a = blockIdx.x - z * kN;

    // phase 0: radial basis for all 192 edges (b = tid), packed bf16 into LDS
    if (tid < kN) {
        const int b = tid;
        const float ax = xyz[(z * kN + a) * 3 + 0];
        const float ay = xyz[(z * kN + a) * 3 + 1];
        const float az = xyz[(z * kN + a) * 3 + 2];
        const float dx = xyz[(z * kN + b) * 3 + 0] - ax;
        const float dy = xyz[(z * kN + b) * 3 + 1] - ay;
        const float dz = xyz[(z * kN + b) * 3 + 2] - az;
        const float d  = sqrtf(fmaf(dx, dx, fmaf(dy, dy, fmaf(dz, dz, 1e-12f))));
        const float dn = d * (19.0f / 10.0f);   // y_k = clamp(dn - k, -1, 1)
        unsigned int pk[16];
#pragma unroll
        for (int q = 0; q < 16; ++q) {
            float v0 = 0.f, v1 = 0.f;
            if (2 * q < kNB) {
                float y = fminf(1.f, fmaxf(-1.f, dn - (float)(2 * q)));
                v0 = __cosf(1.57079632679f * y);
            }
            if (2 * q + 1 < kNB) {
                float y = fminf(1.f, fmaxf(-1.f, dn - (float)(2 * q + 1)));
                v1 = __cosf(1.57079632679f * y);
            }
            pk[q] = bf16pk(v0, v1);
        }
#pragma unroll
        for (int kb = 0; kb < 4; ++kb) {
            uint4 u = make_uint4(pk[4 * kb], pk[4 * kb + 1], pk[4 * kb + 2], pk[4 * kb + 3]);
            *reinterpret_cast<uint4*>(&rbb[(kb * kN + b) * 8]) = u;
        }
    }

    // per-lane weight B-frags in registers (direct global loads, L1/L2-cached)
    bf16x8 w0g[4];
    bf16x8 w1g[2][4];
    float b0v[4], b1v[4];
#pragma unroll
    for (int nt = 0; nt < 4; ++nt) {
        const int n = nt * 16 + l15;
        union { bf16x8 v; unsigned short s[8]; } u;
#pragma unroll
        for (int i = 0; i < 8; ++i) {
            const int k = 8 * g + i;
            u.s[i] = (k < kNB) ? bf16r(W0[k * kH + n]) : (unsigned short)0;
        }
        w0g[nt] = u.v;
        b0v[nt] = b0[n];
        b1v[nt] = b1[n];
    }
#pragma unroll
    for (int ks = 0; ks < 2; ++ks)
#pragma unroll
        for (int nt = 0; nt < 4; ++nt) {
            const int n = nt * 16 + l15;
            union { bf16x8 v; unsigned short s[8]; } u;
#pragma unroll
            for (int i = 0; i < 8; ++i) {
                const int k = ks * 32 + 8 * g + i;
                u.s[i] = bf16r(W1[k * kH + n]);
            }
            w1g[ks][nt] = u.v;
        }

    __syncthreads();   // rbb ready (cross-wave)

    unsigned short* hp = h2b + (size_t)blockIdx.x * kN * kH;

#pragma unroll
    for (int t = 0; t < 3; ++t) {
        const int m0 = (wave * 3 + t) * 16;

        // GEMM-1: h1[16 e][64 h] = rb[16 e][K=32] @ W0[32][64]
        const bf16x8 aR = *reinterpret_cast<const bf16x8*>(&rbb[(g * kN + m0 + l15) * 8]);
#pragma unroll
        for (int nt = 0; nt < 4; ++nt) {
            f32x4 acc = {b0v[nt], b0v[nt], b0v[nt], b0v[nt]};
            acc = __builtin_amdgcn_mfma_f32_16x16x32_bf16(aR, w0g[nt], acc, 0, 0, 0);
            const int h = nt * 16 + l15;
            const int kb = h >> 3, kk = h & 7;
#pragma unroll
            for (int r = 0; r < 4; ++r) {
                const int e = m0 + 4 * g + r;              // C row (verified layout)
                h1b[(kb * kN + e) * 8 + kk] = bf16r(fmaxf(acc[r], 0.f));
            }
        }
        // wave-private h1b region; compiler orders same-wave LDS w->r

        // GEMM-2: h2[16 e][64] = h1[16 e][K=64] @ W1[64][64]
        f32x4 acc2[4];
#pragma unroll
        for (int nt = 0; nt < 4; ++nt)
            acc2[nt] = (f32x4){b1v[nt], b1v[nt], b1v[nt], b1v[nt]};
#pragma unroll
        for (int ks = 0; ks < 2; ++ks) {
            const bf16x8 aH =
                *reinterpret_cast<const bf16x8*>(&h1b[((ks * 4 + g) * kN + m0 + l15) * 8]);
#pragma unroll
            for (int nt = 0; nt < 4; ++nt)
                acc2[nt] = __builtin_amdgcn_mfma_f32_16x16x32_bf16(aH, w1g[ks][nt], acc2[nt], 0, 0, 0);
        }
#pragma unroll
        for (int nt = 0; nt < 4; ++nt) {
            const int h = nt * 16 + l15;
#pragma unroll
            for (int r = 0; r < 4; ++r) {
                const int e = m0 + 4 * g + r;
                hp[(size_t)e * kH + h] = bf16r(fmaxf(acc2[nt][r], 0.f));
            }
        }
    }
}

// ---------------- gemm (MFMA): partial[zc,a,i] = sum_{k in chunk} h2[a,k] G[k,i] ----------------
__global__ __launch_bounds__(256) void gemm_mfma_kernel(
    const unsigned short* __restrict__ h2b,  // [z*N, kK] bf16
    const float* __restrict__ G,             // [z, kK, 32] f32
    float* __restrict__ partial)             // [zc, kN, 32]
{
    __shared__ __align__(16) unsigned short h2s[16 * kN * 8];  // [kb16][a192][8] 48KB
    __shared__ __align__(16) unsigned short gs[16 * kC * 8];   // [kb16][n32][8]   8KB

    const int tid  = threadIdx.x;
    const int wave = tid >> 6, lane = tid & 63;
    const int g = lane >> 4, l15 = lane & 15;
    const int zc = blockIdx.x, z = zc / kNC, c = zc - z * kNC;
    const int K0 = c * kKC;

    // stage h2 chunk [192 a][128 k] bf16 (row-major global -> k-blocked LDS)
#pragma unroll
    for (int p = 0; p < 12; ++p) {
        const int idx = tid + p * 256;        // 0..3071
        const int kb = idx & 15, aa = idx >> 4;
        const uint4 u = *reinterpret_cast<const uint4*>(
            h2b + ((size_t)(z * kN + aa)) * kK + K0 + kb * 8);
        *reinterpret_cast<uint4*>(&h2s[(kb * kN + aa) * 8]) = u;
    }
    // stage G chunk [128 k][32 n] f32 -> bf16 pairs
    {
        const int n = tid & 31, kp0 = tid >> 5;
#pragma unroll
        for (int p = 0; p < 8; ++p) {
            const int k = 2 * (kp0 + p * 8);
            const float lo = G[((size_t)z * kK + K0 + k) * kC + n];
            const float hi = G[((size_t)z * kK + K0 + k + 1) * kC + n];
            *reinterpret_cast<unsigned int*>(&gs[((k >> 3) * kC + n) * 8 + (k & 7)]) =
                bf16pk(lo, hi);
        }
    }
    __syncthreads();

    // B-frags (G) in registers
    bf16x8 bG[4][2];
#pragma unroll
    for (int ks = 0; ks < 4; ++ks)
#pragma unroll
        for (int nt = 0; nt < 2; ++nt)
            bG[ks][nt] = *reinterpret_cast<const bf16x8*>(
                &gs[((ks * 4 + g) * kC + nt * 16 + l15) * 8]);

    const int a0 = wave * 48;
#pragma unroll
    for (int mt = 0; mt < 3; ++mt) {
        const int m0 = a0 + mt * 16;
        bf16x8 aF[4];
#pragma unroll
        for (int ks = 0; ks < 4; ++ks)
            aF[ks] = *reinterpret_cast<const bf16x8*>(
                &h2s[((ks * 4 + g) * kN + m0 + l15) * 8]);
        f32x4 acc0 = {0.f, 0.f, 0.f, 0.f}, acc1 = {0.f, 0.f, 0.f, 0.f};
#pragma unroll
        for (int ks = 0; ks < 4; ++ks) {
            acc0 = __builtin_amdgcn_mfma_f32_16x16x32_bf16(aF[ks], bG[ks][0], acc0, 0, 0, 0);
            acc1 = __builtin_amdgcn_mfma_f32_16x16x32_bf16(aF[ks], bG[ks][1], acc1, 0, 0, 0);
        }
        float* pp = partial + ((size_t)zc * kN + m0) * kC;
#pragma unroll
        for (int r = 0; r < 4; ++r) {
            pp[(4 * g + r) * kC + l15]      = acc0[r];
            pp[(4 * g + r) * kC + 16 + l15] = acc1[r];
        }
    }
}

// ---------------- reduce: out = (sum_c partial + b2@S) * mask / sqrt(n) ----------------
__global__ __launch_bounds__(256) void reduce_kernel(
    const float* __restrict__ partial,   // [z*kNC, kN, 32]
    const float* __restrict__ S,         // [B, C]
    const float* __restrict__ b2,        // [C*C]
    const float* __restrict__ mask,      // [B, N]
    float* __restrict__ dst)             // [B, N, C]
{
    const int o = blockIdx.x * 256 + threadIdx.x;   // < 12288
    const int z = o / (kN * kC);
    const int ai = o - z * (kN * kC);
    const int i = ai & 31, a = ai >> 5;
    const float* p = partial + (size_t)z * kNC * kN * kC + ai;
    float acc = 0.f;
#pragma unroll 8
    for (int c = 0; c < kNC; ++c) acc += p[(size_t)c * kN * kC];
    float bt = 0.f;
#pragma unroll
    for (int j = 0; j < kC; ++j) bt = fmaf(b2[i * kC + j], S[z * kC + j], bt);
    dst[o] = (acc + bt) * kInvSqrtN * mask[z * kN + a];
}

} // namespace

extern "C" void kernel_launch(void* const* d_in, const int* in_sizes, int n_in,
                              void* d_out, int out_size, void* d_ws, size_t ws_size,
                              hipStream_t stream) {
    const float* features = (const float*)d_in[0];
    const float* xyz      = (const float*)d_in[1];
    const float* mask     = (const float*)d_in[2];
    const float* W0       = (const float*)d_in[3];
    const float* b0       = (const float*)d_in[4];
    const float* W1       = (const float*)d_in[5];
    const float* b1       = (const float*)d_in[6];
    const float* W2       = (const float*)d_in[7];
    const float* b2       = (const float*)d_in[8];
    float* out = (float*)d_out;

    // workspace layout (floats):
    //   G       :       0 .. 786432          (B*N*H*C)
    //   S       :  786432 .. 786560          (pad)
    //   h2b     :  786560 .. 3145856         (73728*64 bf16 = 2359296 f)
    //   partial : 3145856 .. 4325504         (2*96*192*32)
    //   ftmp    : 4325504 .. 4337792
    float* ws = (float*)d_ws;
    float* G        = ws;
    float* S        = ws + 786432;
    unsigned short* h2b = (unsigned short*)(ws + 786560);
    float* partial  = ws + 3145856;
    float* ftmp     = ws + 4325504;

    const float* cur = features;
    for (int l = 0; l < kLayers; ++l) {
        float* dst = (l == kLayers - 1) ? out : ftmp;
        g_kernel<<<kB * kN, 256, 0, stream>>>(cur, W2 + (size_t)l * kH * kC * kC, G);
        s_kernel<<<kB, 256, 0, stream>>>(cur, S);
        edge_mfma_kernel<<<kB * kN, 256, 0, stream>>>(
            xyz,
            W0 + (size_t)l * kNB * kH, b0 + (size_t)l * kH,
            W1 + (size_t)l * kH * kH,  b1 + (size_t)l * kH,
            h2b);
        gemm_mfma_kernel<<<kB * kNC, 256, 0, stream>>>(h2b, G, partial);
        reduce_kernel<<<(kB * kN * kC) / 256, 256, 0, stream>>>(
            partial, S, b2 + (size_t)l * kC * kC, mask, dst);
        cur = dst;
    }
}

// Round 6
// 92.097 us; speedup vs baseline: 2.7931x; 1.2129x over previous
//
#include <hip/hip_runtime.h>
#include <math.h>

namespace {

constexpr int kB  = 2;
constexpr int kN  = 192;
constexpr int kC  = 32;
constexpr int kH  = 64;
constexpr int kNB = 20;
constexpr int kLayers = 2;
constexpr int kK  = kN * kH;      // 12288 contraction length per z
constexpr int kKB = kK / 8;       // 1536 kb-groups (8 k each) per z
constexpr int kKC = 128;          // K-chunk per gemm block
constexpr int kNC = kK / kKC;     // 96 chunks per z
constexpr float kInvSqrtN = 0.07216878364870323f;  // 1/sqrt(192)

typedef __attribute__((ext_vector_type(8))) short bf16x8;
typedef __attribute__((ext_vector_type(4))) float f32x4;

__device__ inline unsigned short bf16r(float x) {   // RNE f32->bf16
    unsigned int u = __float_as_uint(x);
    u = (u + 0x7FFFu + ((u >> 16) & 1u)) >> 16;
    return (unsigned short)u;
}
__device__ inline unsigned int bf16pk(float lo, float hi) {
    return (unsigned int)bf16r(lo) | ((unsigned int)bf16r(hi) << 16);
}

// ---------------- init: rb frags (layer-invariant) + packed W0/W1 frags ----------------
// rbg[z][a][kb=0..3][b=0..191][8]  (k = kb*8+i, zero-padded past kNB)
// wb0[l][kb=0..3][n=0..63][8]      (k = kb*8+i)   -> layer stride 2048 ushorts
// wb1[l][kb=0..7][n=0..63][8]                     -> layer stride 4096 ushorts
__global__ __launch_bounds__(256) void init_kernel(
    const float* __restrict__ xyz,
    const float* __restrict__ W0,
    const float* __restrict__ W1,
    unsigned short* __restrict__ rbg,
    unsigned short* __restrict__ wb0,
    unsigned short* __restrict__ wb1)
{
    const int tid = threadIdx.x, blk = blockIdx.x;
    if (blk < 288) {
        const int E = blk * 256 + tid;          // 0..73727
        const int z = E / (kN * kN);
        const int r = E - z * (kN * kN);
        const int a = r / kN, b = r - a * kN;
        const float ax = xyz[(z * kN + a) * 3 + 0];
        const float ay = xyz[(z * kN + a) * 3 + 1];
        const float az = xyz[(z * kN + a) * 3 + 2];
        const float dx = xyz[(z * kN + b) * 3 + 0] - ax;
        const float dy = xyz[(z * kN + b) * 3 + 1] - ay;
        const float dz = xyz[(z * kN + b) * 3 + 2] - az;
        const float d  = sqrtf(fmaf(dx, dx, fmaf(dy, dy, fmaf(dz, dz, 1e-12f))));
        const float dn = d * (19.0f / 10.0f);   // y_k = clamp(dn - k, -1, 1)
        unsigned int pk[16];
#pragma unroll
        for (int q = 0; q < 16; ++q) {
            float v0 = 0.f, v1 = 0.f;
            if (2 * q < kNB) {
                float y = fminf(1.f, fmaxf(-1.f, dn - (float)(2 * q)));
                v0 = __cosf(1.57079632679f * y);
            }
            if (2 * q + 1 < kNB) {
                float y = fminf(1.f, fmaxf(-1.f, dn - (float)(2 * q + 1)));
                v1 = __cosf(1.57079632679f * y);
            }
            pk[q] = bf16pk(v0, v1);
        }
#pragma unroll
        for (int kb = 0; kb < 4; ++kb) {
            uint4 u = make_uint4(pk[4 * kb], pk[4 * kb + 1], pk[4 * kb + 2], pk[4 * kb + 3]);
            *reinterpret_cast<uint4*>(&rbg[(((size_t)(z * kN + a) * 4 + kb) * kN + b) * 8]) = u;
        }
    } else if (blk == 288) {
        // W0 pack: 512 groups (l,kb,n): grp = (l*4+kb)*64 + n
#pragma unroll
        for (int q = 0; q < 2; ++q) {
            const int grp = tid * 2 + q;
            const int l = grp >> 8, kb = (grp >> 6) & 3, n = grp & 63;
            union { bf16x8 v; unsigned short s[8]; } u;
#pragma unroll
            for (int i = 0; i < 8; ++i) {
                const int k = kb * 8 + i;
                u.s[i] = (k < kNB) ? bf16r(W0[(l * kNB + k) * kH + n]) : (unsigned short)0;
            }
            *reinterpret_cast<bf16x8*>(&wb0[(size_t)grp * 8]) = u.v;
        }
    } else {
        // W1 pack: 1024 groups (l,kb,n): grp = (l*8+kb)*64 + n
#pragma unroll
        for (int q = 0; q < 4; ++q) {
            const int grp = tid * 4 + q;
            const int l = grp >> 9, kb = (grp >> 6) & 7, n = grp & 63;
            union { bf16x8 v; unsigned short s[8]; } u;
#pragma unroll
            for (int i = 0; i < 8; ++i) {
                const int k = kb * 8 + i;
                u.s[i] = bf16r(W1[(l * kH + k) * kH + n]);
            }
            *reinterpret_cast<bf16x8*>(&wb1[(size_t)grp * 8]) = u.v;
        }
    }
}

// ---------------- edge kernel: block=(z,a); fuses G-row compute + edge MLP ----------------
// Gb[z][kb=b*8+h/8][i=0..31][8]   (k = b*64+h)
// h2g[z][kb=b*8+h/8][a=0..191][8]
__global__ __launch_bounds__(256) void edge_kernel(
    const float* __restrict__ feat,   // [B*N, C] layer input
    const float* __restrict__ W2,     // [H, C*C] (layer-offset)
    const float* __restrict__ b0,     // [H]
    const float* __restrict__ b1,     // [H]
    const unsigned short* __restrict__ rbg,
    const unsigned short* __restrict__ wb0,   // layer-offset
    const unsigned short* __restrict__ wb1,   // layer-offset
    unsigned short* __restrict__ Gb,
    unsigned short* __restrict__ h2g)
{
    __shared__ float fsh[kC];
    __shared__ __align__(16) unsigned short h1b[4 * 1024];  // 8 KB, wave-private slices

    const int tid  = threadIdx.x;
    const int wave = tid >> 6, lane = tid & 63;
    const int g = lane >> 4, l15 = lane & 15;
    const int z = blockIdx.x / kN, a = blockIdx.x - z * kN;

    if (tid < kC) fsh[tid] = feat[(z * kN + a) * kC + tid];
    __syncthreads();

    // --- fused g-work: G row for b-row = a ---
#pragma unroll
    for (int p = 0; p < 8; ++p) {
        const int idx = tid + 256 * p;          // 0..2047 = h*32+i
        const int h = idx >> 5, i = idx & 31;
        const float* w = W2 + h * (kC * kC) + i * kC;
        float s = 0.f;
#pragma unroll
        for (int j = 0; j < kC; j += 4) {
            const float4 w4 = *reinterpret_cast<const float4*>(&w[j]);
            s = fmaf(w4.x, fsh[j], s);
            s = fmaf(w4.y, fsh[j + 1], s);
            s = fmaf(w4.z, fsh[j + 2], s);
            s = fmaf(w4.w, fsh[j + 3], s);
        }
        Gb[((size_t)(z * kKB + a * 8 + (h >> 3)) * kC + i) * 8 + (h & 7)] = bf16r(s);
    }

    // --- per-lane weight frags (pre-packed, L2 broadcast) ---
    bf16x8 w0g[4], w1g[2][4];
    float b0v[4], b1v[4];
#pragma unroll
    for (int nt = 0; nt < 4; ++nt) {
        const int n = nt * 16 + l15;
        w0g[nt] = *reinterpret_cast<const bf16x8*>(&wb0[((size_t)g * kH + n) * 8]);
        b0v[nt] = b0[n];
        b1v[nt] = b1[n];
    }
#pragma unroll
    for (int ks = 0; ks < 2; ++ks)
#pragma unroll
        for (int nt = 0; nt < 4; ++nt)
            w1g[ks][nt] = *reinterpret_cast<const bf16x8*>(
                &wb1[((size_t)(ks * 4 + g) * kH + nt * 16 + l15) * 8]);

    unsigned short* h1w = h1b + wave * 1024;
    const unsigned short* rbp = rbg + (size_t)(z * kN + a) * 4 * kN * 8;

#pragma unroll
    for (int t = 0; t < 3; ++t) {
        const int m0 = (wave * 3 + t) * 16;

        // GEMM-1: h1[16 e][64 h] = rb[16 e][K=32] @ W0[32][64]
        const bf16x8 aR = *reinterpret_cast<const bf16x8*>(&rbp[((size_t)g * kN + m0 + l15) * 8]);
#pragma unroll
        for (int nt = 0; nt < 4; ++nt) {
            f32x4 acc = {b0v[nt], b0v[nt], b0v[nt], b0v[nt]};
            acc = __builtin_amdgcn_mfma_f32_16x16x32_bf16(aR, w0g[nt], acc, 0, 0, 0);
            const int h = nt * 16 + l15;
            const int kb = h >> 3, kk = h & 7;
#pragma unroll
            for (int r = 0; r < 4; ++r)
                h1w[(kb * 16 + 4 * g + r) * 8 + kk] = bf16r(fmaxf(acc[r], 0.f));
        }
        // wave-private h1 region; compiler enforces same-wave LDS RAW via lgkmcnt

        // GEMM-2: h2[16 e][64] = h1[16 e][K=64] @ W1[64][64]
        f32x4 acc2[4];
#pragma unroll
        for (int nt = 0; nt < 4; ++nt)
            acc2[nt] = (f32x4){b1v[nt], b1v[nt], b1v[nt], b1v[nt]};
#pragma unroll
        for (int ks = 0; ks < 2; ++ks) {
            const bf16x8 aH = *reinterpret_cast<const bf16x8*>(
                &h1w[((ks * 4 + g) * 16 + l15) * 8]);
#pragma unroll
            for (int nt = 0; nt < 4; ++nt)
                acc2[nt] = __builtin_amdgcn_mfma_f32_16x16x32_bf16(aH, w1g[ks][nt], acc2[nt], 0, 0, 0);
        }
#pragma unroll
        for (int nt = 0; nt < 4; ++nt) {
            const int h = nt * 16 + l15;
#pragma unroll
            for (int r = 0; r < 4; ++r) {
                const int b = m0 + 4 * g + r;   // edge index (row of C)
                h2g[((size_t)(z * kKB + b * 8 + (h >> 3)) * kN + a) * 8 + (h & 7)] =
                    bf16r(fmaxf(acc2[nt][r], 0.f));
            }
        }
    }
}

// ---------------- gemm: LDS-free split-K MFMA ----------------
// partial[zc][a=192][i=32] = sum_{k in chunk c} h2[a,k] * G[k,i]
__global__ __launch_bounds__(256) void gemm_kernel(
    const unsigned short* __restrict__ h2g,
    const unsigned short* __restrict__ Gb,
    float* __restrict__ partial)
{
    const int tid  = threadIdx.x;
    const int wave = tid >> 6, lane = tid & 63;
    const int g = lane >> 4, l15 = lane & 15;
    const int zc = blockIdx.x, z = zc / kNC, c = zc - z * kNC;
    const int kb0 = z * kKB + c * 16;

    bf16x8 bG[4][2];
#pragma unroll
    for (int ks = 0; ks < 4; ++ks)
#pragma unroll
        for (int nt = 0; nt < 2; ++nt)
            bG[ks][nt] = *reinterpret_cast<const bf16x8*>(
                &Gb[((size_t)(kb0 + ks * 4 + g) * kC + nt * 16 + l15) * 8]);

    const int a0 = wave * 48;
#pragma unroll
    for (int mt = 0; mt < 3; ++mt) {
        const int m0 = a0 + mt * 16;
        f32x4 acc0 = {0.f, 0.f, 0.f, 0.f}, acc1 = {0.f, 0.f, 0.f, 0.f};
#pragma unroll
        for (int ks = 0; ks < 4; ++ks) {
            const bf16x8 aF = *reinterpret_cast<const bf16x8*>(
                &h2g[((size_t)(kb0 + ks * 4 + g) * kN + m0 + l15) * 8]);
            acc0 = __builtin_amdgcn_mfma_f32_16x16x32_bf16(aF, bG[ks][0], acc0, 0, 0, 0);
            acc1 = __builtin_amdgcn_mfma_f32_16x16x32_bf16(aF, bG[ks][1], acc1, 0, 0, 0);
        }
        float* pp = partial + ((size_t)zc * kN + m0) * kC;
#pragma unroll
        for (int r = 0; r < 4; ++r) {
            pp[(4 * g + r) * kC + l15]      = acc0[r];
            pp[(4 * g + r) * kC + 16 + l15] = acc1[r];
        }
    }
}

// ---------------- reduce: out = (sum_c partial + b2@S) * mask / sqrt(n) ----------------
__global__ __launch_bounds__(256) void reduce_kernel(
    const float* __restrict__ partial,   // [z*kNC, kN, 32]
    const float* __restrict__ feat,      // [B*N, C] layer input (for S)
    const float* __restrict__ b2,        // [C*C] (layer-offset)
    const float* __restrict__ mask,      // [B, N]
    float* __restrict__ dst)             // [B, N, C]
{
    __shared__ float red[8][kC];
    __shared__ float Ssh[kC];
    const int tid = threadIdx.x;
    const int z = blockIdx.x / 24;               // 24 blocks per z

    // redundant per-block S[z,j] = sum_b feat[z,b,j]
    {
        const int j = tid & 31, s = tid >> 5;
        float acc = 0.f;
        for (int b = s * 24; b < s * 24 + 24; ++b) acc += feat[(z * kN + b) * kC + j];
        red[s][j] = acc;
    }
    __syncthreads();
    if (tid < kC) {
        float v = 0.f;
#pragma unroll
        for (int q = 0; q < 8; ++q) v += red[q][tid];
        Ssh[tid] = v;
    }
    __syncthreads();

    const int o  = blockIdx.x * 256 + tid;       // < 12288
    const int ai = o - z * (kN * kC);
    const int i = ai & 31, a = ai >> 5;
    const float* p = partial + (size_t)z * kNC * kN * kC + ai;
    float acc = 0.f;
#pragma unroll 8
    for (int c = 0; c < kNC; ++c) acc += p[(size_t)c * kN * kC];
    float bt = 0.f;
#pragma unroll
    for (int j = 0; j < kC; ++j) bt = fmaf(b2[i * kC + j], Ssh[j], bt);
    dst[o] = (acc + bt) * kInvSqrtN * mask[z * kN + a];
}

} // namespace

extern "C" void kernel_launch(void* const* d_in, const int* in_sizes, int n_in,
                              void* d_out, int out_size, void* d_ws, size_t ws_size,
                              hipStream_t stream) {
    const float* features = (const float*)d_in[0];
    const float* xyz      = (const float*)d_in[1];
    const float* mask     = (const float*)d_in[2];
    const float* W0       = (const float*)d_in[3];
    const float* b0       = (const float*)d_in[4];
    const float* W1       = (const float*)d_in[5];
    const float* b1       = (const float*)d_in[6];
    const float* W2       = (const float*)d_in[7];
    const float* b2       = (const float*)d_in[8];
    float* out = (float*)d_out;

    // workspace layout (float offsets):
    //   rbg    :       0 .. 1179648   (2359296 ushort)
    //   wb0    : 1179648 .. 1181696   (4096 ushort = 2 layers x 2048)
    //   wb1    : 1181696 .. 1185792   (8192 ushort = 2 layers x 4096)
    //   Gb     : 1185792 .. 1579008   (786432 ushort)
    //   h2g    : 1579008 .. 3938304   (4718592 ushort)
    //   partial: 3938304 .. 5117952   (1179648 f)
    //   ftmp   : 5117952 .. 5130240
    float* ws = (float*)d_ws;
    unsigned short* rbg = (unsigned short*)(ws);
    unsigned short* wb0 = (unsigned short*)(ws + 1179648);
    unsigned short* wb1 = (unsigned short*)(ws + 1181696);
    unsigned short* Gb  = (unsigned short*)(ws + 1185792);
    unsigned short* h2g = (unsigned short*)(ws + 1579008);
    float* partial = ws + 3938304;
    float* ftmp    = ws + 5117952;

    init_kernel<<<290, 256, 0, stream>>>(xyz, W0, W1, rbg, wb0, wb1);

    const float* cur = features;
    for (int l = 0; l < kLayers; ++l) {
        float* dst = (l == kLayers - 1) ? out : ftmp;
        edge_kernel<<<kB * kN, 256, 0, stream>>>(
            cur, W2 + (size_t)l * kH * kC * kC,
            b0 + (size_t)l * kH, b1 + (size_t)l * kH,
            rbg, wb0 + (size_t)l * 2048, wb1 + (size_t)l * 4096,   // FIX: ushort strides
            Gb, h2g);
        gemm_kernel<<<kB * kNC, 256, 0, stream>>>(h2g, Gb, partial);
        reduce_kernel<<<(kB * kN * kC) / 256, 256, 0, stream>>>(
            partial, cur, b2 + (size_t)l * kC * kC, mask, dst);
        cur = dst;
    }
}

// Round 7
// 91.107 us; speedup vs baseline: 2.8235x; 1.0109x over previous
//
#include <hip/hip_runtime.h>
#include <math.h>

namespace {

constexpr int kB  = 2;
constexpr int kN  = 192;
constexpr int kC  = 32;
constexpr int kH  = 64;
constexpr int kNB = 20;
constexpr int kLayers = 2;
constexpr int kK  = kN * kH;      // 12288 contraction length per z
constexpr int kKB = kK / 8;       // 1536 kb-groups (8 k each) per z
constexpr int kKC = 128;          // K-chunk per gemm block
constexpr int kNC = kK / kKC;     // 96 chunks per z
constexpr float kInvSqrtN = 0.07216878364870323f;  // 1/sqrt(192)

typedef __attribute__((ext_vector_type(8))) short bf16x8;
typedef __attribute__((ext_vector_type(4))) float f32x4;

__device__ inline unsigned short bf16r(float x) {   // RNE f32->bf16
    unsigned int u = __float_as_uint(x);
    u = (u + 0x7FFFu + ((u >> 16) & 1u)) >> 16;
    return (unsigned short)u;
}

// ---------------- init: packed W0/W1 frags only (2 blocks) ----------------
// wb0[l][kb=0..3][n=0..63][8]  (k = kb*8+i, zero-padded past kNB) -> 2048 ushort/layer
// wb1[l][kb=0..7][n=0..63][8]                                     -> 4096 ushort/layer
__global__ __launch_bounds__(256) void init_kernel(
    const float* __restrict__ W0,
    const float* __restrict__ W1,
    unsigned short* __restrict__ wb0,
    unsigned short* __restrict__ wb1)
{
    const int tid = threadIdx.x;
    if (blockIdx.x == 0) {
        // W0 pack: 512 groups (l,kb,n): grp = (l*4+kb)*64 + n
#pragma unroll
        for (int q = 0; q < 2; ++q) {
            const int grp = tid * 2 + q;
            const int l = grp >> 8, kb = (grp >> 6) & 3, n = grp & 63;
            union { bf16x8 v; unsigned short s[8]; } u;
#pragma unroll
            for (int i = 0; i < 8; ++i) {
                const int k = kb * 8 + i;
                u.s[i] = (k < kNB) ? bf16r(W0[(l * kNB + k) * kH + n]) : (unsigned short)0;
            }
            *reinterpret_cast<bf16x8*>(&wb0[(size_t)grp * 8]) = u.v;
        }
    } else {
        // W1 pack: 1024 groups (l,kb,n): grp = (l*8+kb)*64 + n
#pragma unroll
        for (int q = 0; q < 4; ++q) {
            const int grp = tid * 4 + q;
            const int l = grp >> 9, kb = (grp >> 6) & 7, n = grp & 63;
            union { bf16x8 v; unsigned short s[8]; } u;
#pragma unroll
            for (int i = 0; i < 8; ++i) {
                const int k = kb * 8 + i;
                u.s[i] = bf16r(W1[(l * kH + k) * kH + n]);
            }
            *reinterpret_cast<bf16x8*>(&wb1[(size_t)grp * 8]) = u.v;
        }
    }
}

// ---------------- edge kernel: block=(z,bcol). rb symmetry: d(a,b)=d(b,a). ----------------
// Computes h2[a][h] for ALL 192 a-rows of one b-endpoint, plus G row for b=bcol.
// Gb[z][kb=b*8+h/8][i=0..31][8], h2g[z][kb=b*8+h/8][a=0..191][8]
// -> all global stores land in block-exclusive contiguous regions (4KB / 24KB).
__global__ __launch_bounds__(256) void edge_kernel(
    const float* __restrict__ feat,   // [B*N, C] layer input
    const float* __restrict__ W2,     // [H, C*C] (layer-offset)
    const float* __restrict__ b0,     // [H]
    const float* __restrict__ b1,     // [H]
    const float* __restrict__ xyz,    // [B,N,3]
    const unsigned short* __restrict__ wb0,   // layer-offset
    const unsigned short* __restrict__ wb1,   // layer-offset
    unsigned short* __restrict__ Gb,
    unsigned short* __restrict__ h2g)
{
    __shared__ float fsh[kC];
    __shared__ __align__(16) unsigned short h1b[4 * 1024];  // 8 KB, wave-private slices

    const int tid  = threadIdx.x;
    const int wave = tid >> 6, lane = tid & 63;
    const int g = lane >> 4, l15 = lane & 15;
    const int z = blockIdx.x / kN, bcol = blockIdx.x - z * kN;

    if (tid < kC) fsh[tid] = feat[(z * kN + bcol) * kC + tid];
    __syncthreads();

    // --- fused g-work: G row for b-row = bcol (block-exclusive 4KB region) ---
#pragma unroll
    for (int p = 0; p < 8; ++p) {
        const int idx = tid + 256 * p;          // 0..2047 = h*32+i
        const int h = idx >> 5, i = idx & 31;
        const float* w = W2 + h * (kC * kC) + i * kC;
        float s = 0.f;
#pragma unroll
        for (int j = 0; j < kC; j += 4) {
            const float4 w4 = *reinterpret_cast<const float4*>(&w[j]);
            s = fmaf(w4.x, fsh[j], s);
            s = fmaf(w4.y, fsh[j + 1], s);
            s = fmaf(w4.z, fsh[j + 2], s);
            s = fmaf(w4.w, fsh[j + 3], s);
        }
        Gb[((size_t)(z * kKB + bcol * 8 + (h >> 3)) * kC + i) * 8 + (h & 7)] = bf16r(s);
    }

    // --- per-lane weight frags (pre-packed, L2 broadcast) ---
    bf16x8 w0g[4], w1g[2][4];
    float b0v[4], b1v[4];
#pragma unroll
    for (int nt = 0; nt < 4; ++nt) {
        const int n = nt * 16 + l15;
        w0g[nt] = *reinterpret_cast<const bf16x8*>(&wb0[((size_t)g * kH + n) * 8]);
        b0v[nt] = b0[n];
        b1v[nt] = b1[n];
    }
#pragma unroll
    for (int ks = 0; ks < 2; ++ks)
#pragma unroll
        for (int nt = 0; nt < 4; ++nt)
            w1g[ks][nt] = *reinterpret_cast<const bf16x8*>(
                &wb1[((size_t)(ks * 4 + g) * kH + nt * 16 + l15) * 8]);

    const float bx = xyz[(z * kN + bcol) * 3 + 0];
    const float by = xyz[(z * kN + bcol) * 3 + 1];
    const float bz = xyz[(z * kN + bcol) * 3 + 2];

    unsigned short* h1w = h1b + wave * 1024;

#pragma unroll
    for (int t = 0; t < 3; ++t) {
        const int m0 = (wave * 3 + t) * 16;

        // A-frag: rb for edge (arow = m0+l15, bcol), k = 8g+i, computed in-register
        const int arow = m0 + l15;
        const float dx = xyz[(z * kN + arow) * 3 + 0] - bx;
        const float dy = xyz[(z * kN + arow) * 3 + 1] - by;
        const float dz = xyz[(z * kN + arow) * 3 + 2] - bz;
        const float d  = sqrtf(fmaf(dx, dx, fmaf(dy, dy, fmaf(dz, dz, 1e-12f))));
        const float dn = d * (19.0f / 10.0f);   // y_k = clamp(dn - k, -1, 1)
        union { bf16x8 v; unsigned short s[8]; } aU;
#pragma unroll
        for (int i = 0; i < 8; ++i) {
            const float y = fminf(1.f, fmaxf(-1.f, dn - (float)(8 * g + i)));
            aU.s[i] = bf16r(__cosf(1.57079632679f * y));
        }
        const bf16x8 aR = aU.v;   // k>=20 entries multiply zero-padded W0 frags

        // GEMM-1: h1[16 a][64 h] = rb[16 a][K=32] @ W0[32][64]
#pragma unroll
        for (int nt = 0; nt < 4; ++nt) {
            f32x4 acc = {b0v[nt], b0v[nt], b0v[nt], b0v[nt]};
            acc = __builtin_amdgcn_mfma_f32_16x16x32_bf16(aR, w0g[nt], acc, 0, 0, 0);
            const int h = nt * 16 + l15;
            const int kb = h >> 3, kk = h & 7;
#pragma unroll
            for (int r = 0; r < 4; ++r)
                h1w[(kb * 16 + 4 * g + r) * 8 + kk] = bf16r(fmaxf(acc[r], 0.f));
        }
        // wave-private h1 region; same-wave LDS RAW ordered via lgkmcnt

        // GEMM-2: h2[16 a][64] = h1[16 a][K=64] @ W1[64][64]
        f32x4 acc2[4];
#pragma unroll
        for (int nt = 0; nt < 4; ++nt)
            acc2[nt] = (f32x4){b1v[nt], b1v[nt], b1v[nt], b1v[nt]};
#pragma unroll
        for (int ks = 0; ks < 2; ++ks) {
            const bf16x8 aH = *reinterpret_cast<const bf16x8*>(
                &h1w[((ks * 4 + g) * 16 + l15) * 8]);
#pragma unroll
            for (int nt = 0; nt < 4; ++nt)
                acc2[nt] = __builtin_amdgcn_mfma_f32_16x16x32_bf16(aH, w1g[ks][nt], acc2[nt], 0, 0, 0);
        }
#pragma unroll
        for (int nt = 0; nt < 4; ++nt) {
            const int h = nt * 16 + l15;
#pragma unroll
            for (int r = 0; r < 4; ++r) {
                const int ar = m0 + 4 * g + r;   // a row (row of C)
                h2g[((size_t)(z * kKB + bcol * 8 + (h >> 3)) * kN + ar) * 8 + (h & 7)] =
                    bf16r(fmaxf(acc2[nt][r], 0.f));
            }
        }
    }
}

// ---------------- gemm: LDS-free split-K MFMA ----------------
// partial[zc][a=192][i=32] = sum_{k in chunk c} h2[a,k] * G[k,i]
__global__ __launch_bounds__(256) void gemm_kernel(
    const unsigned short* __restrict__ h2g,
    const unsigned short* __restrict__ Gb,
    float* __restrict__ partial)
{
    const int tid  = threadIdx.x;
    const int wave = tid >> 6, lane = tid & 63;
    const int g = lane >> 4, l15 = lane & 15;
    const int zc = blockIdx.x, z = zc / kNC, c = zc - z * kNC;
    const int kb0 = z * kKB + c * 16;

    bf16x8 bG[4][2];
#pragma unroll
    for (int ks = 0; ks < 4; ++ks)
#pragma unroll
        for (int nt = 0; nt < 2; ++nt)
            bG[ks][nt] = *reinterpret_cast<const bf16x8*>(
                &Gb[((size_t)(kb0 + ks * 4 + g) * kC + nt * 16 + l15) * 8]);

    const int a0 = wave * 48;
#pragma unroll
    for (int mt = 0; mt < 3; ++mt) {
        const int m0 = a0 + mt * 16;
        f32x4 acc0 = {0.f, 0.f, 0.f, 0.f}, acc1 = {0.f, 0.f, 0.f, 0.f};
#pragma unroll
        for (int ks = 0; ks < 4; ++ks) {
            const bf16x8 aF = *reinterpret_cast<const bf16x8*>(
                &h2g[((size_t)(kb0 + ks * 4 + g) * kN + m0 + l15) * 8]);
            acc0 = __builtin_amdgcn_mfma_f32_16x16x32_bf16(aF, bG[ks][0], acc0, 0, 0, 0);
            acc1 = __builtin_amdgcn_mfma_f32_16x16x32_bf16(aF, bG[ks][1], acc1, 0, 0, 0);
        }
        float* pp = partial + ((size_t)zc * kN + m0) * kC;
#pragma unroll
        for (int r = 0; r < 4; ++r) {
            pp[(4 * g + r) * kC + l15]      = acc0[r];
            pp[(4 * g + r) * kC + 16 + l15] = acc1[r];
        }
    }
}

// ---------------- reduce: out = (sum_c partial + b2@S) * mask / sqrt(n) ----------------
__global__ __launch_bounds__(256) void reduce_kernel(
    const float* __restrict__ partial,   // [z*kNC, kN, 32]
    const float* __restrict__ feat,      // [B*N, C] layer input (for S)
    const float* __restrict__ b2,        // [C*C] (layer-offset)
    const float* __restrict__ mask,      // [B, N]
    float* __restrict__ dst)             // [B, N, C]
{
    __shared__ float red[8][kC];
    __shared__ float Ssh[kC];
    const int tid = threadIdx.x;
    const int z = blockIdx.x / 24;               // 24 blocks per z

    // redundant per-block S[z,j] = sum_b feat[z,b,j]
    {
        const int j = tid & 31, s = tid >> 5;
        float acc = 0.f;
        for (int b = s * 24; b < s * 24 + 24; ++b) acc += feat[(z * kN + b) * kC + j];
        red[s][j] = acc;
    }
    __syncthreads();
    if (tid < kC) {
        float v = 0.f;
#pragma unroll
        for (int q = 0; q < 8; ++q) v += red[q][tid];
        Ssh[tid] = v;
    }
    __syncthreads();

    const int o  = blockIdx.x * 256 + tid;       // < 12288
    const int ai = o - z * (kN * kC);
    const int i = ai & 31, a = ai >> 5;
    const float* p = partial + (size_t)z * kNC * kN * kC + ai;
    float acc = 0.f;
#pragma unroll 8
    for (int c = 0; c < kNC; ++c) acc += p[(size_t)c * kN * kC];
    float bt = 0.f;
#pragma unroll
    for (int j = 0; j < kC; ++j) bt = fmaf(b2[i * kC + j], Ssh[j], bt);
    dst[o] = (acc + bt) * kInvSqrtN * mask[z * kN + a];
}

} // namespace

extern "C" void kernel_launch(void* const* d_in, const int* in_sizes, int n_in,
                              void* d_out, int out_size, void* d_ws, size_t ws_size,
                              hipStream_t stream) {
    const float* features = (const float*)d_in[0];
    const float* xyz      = (const float*)d_in[1];
    const float* mask     = (const float*)d_in[2];
    const float* W0       = (const float*)d_in[3];
    const float* b0       = (const float*)d_in[4];
    const float* W1       = (const float*)d_in[5];
    const float* b1       = (const float*)d_in[6];
    const float* W2       = (const float*)d_in[7];
    const float* b2       = (const float*)d_in[8];
    float* out = (float*)d_out;

    // workspace layout (float offsets):
    //   wb0    :       0 ..    2048   (4096 ushort  = 2 layers x 2048)
    //   wb1    :    2048 ..    6144   (8192 ushort  = 2 layers x 4096)
    //   Gb     :    6144 ..  399360   (786432 ushort)
    //   h2g    :  399360 .. 2758656   (4718592 ushort)
    //   partial: 2758656 .. 3938304   (1179648 f)
    //   ftmp   : 3938304 .. 3950592
    float* ws = (float*)d_ws;
    unsigned short* wb0 = (unsigned short*)(ws);
    unsigned short* wb1 = (unsigned short*)(ws + 2048);
    unsigned short* Gb  = (unsigned short*)(ws + 6144);
    unsigned short* h2g = (unsigned short*)(ws + 399360);
    float* partial = ws + 2758656;
    float* ftmp    = ws + 3938304;

    init_kernel<<<2, 256, 0, stream>>>(W0, W1, wb0, wb1);

    const float* cur = features;
    for (int l = 0; l < kLayers; ++l) {
        float* dst = (l == kLayers - 1) ? out : ftmp;
        edge_kernel<<<kB * kN, 256, 0, stream>>>(
            cur, W2 + (size_t)l * kH * kC * kC,
            b0 + (size_t)l * kH, b1 + (size_t)l * kH,
            xyz, wb0 + (size_t)l * 2048, wb1 + (size_t)l * 4096,
            Gb, h2g);
        gemm_kernel<<<kB * kNC, 256, 0, stream>>>(h2g, Gb, partial);
        reduce_kernel<<<(kB * kN * kC) / 256, 256, 0, stream>>>(
            partial, cur, b2 + (size_t)l * kC * kC, mask, dst);
        cur = dst;
    }
}

// Round 8
// 82.657 us; speedup vs baseline: 3.1121x; 1.1022x over previous
//
#include <hip/hip_runtime.h>
#include <math.h>

namespace {

constexpr int kB  = 2;
constexpr int kN  = 192;
constexpr int kC  = 32;
constexpr int kH  = 64;
constexpr int kNB = 20;
constexpr int kLayers = 2;
constexpr float kInvSqrtN = 0.07216878364870323f;  // 1/sqrt(192)

typedef __attribute__((ext_vector_type(8))) short bf16x8;
typedef __attribute__((ext_vector_type(4))) float f32x4;

__device__ inline unsigned short bf16r(float x) {   // RNE f32->bf16
    unsigned int u = __float_as_uint(x);
    u = (u + 0x7FFFu + ((u >> 16) & 1u)) >> 16;
    return (unsigned short)u;
}

// ---------------- init: packed W0/W1 frags only (2 blocks) ----------------
// wb0[l][kb=0..3][n=0..63][8]  (k = kb*8+i, zero-padded past kNB) -> 2048 ushort/layer
// wb1[l][kb=0..7][n=0..63][8]                                     -> 4096 ushort/layer
__global__ __launch_bounds__(256) void init_kernel(
    const float* __restrict__ W0,
    const float* __restrict__ W1,
    unsigned short* __restrict__ wb0,
    unsigned short* __restrict__ wb1)
{
    const int tid = threadIdx.x;
    if (blockIdx.x == 0) {
#pragma unroll
        for (int q = 0; q < 2; ++q) {
            const int grp = tid * 2 + q;                 // (l*4+kb)*64 + n
            const int l = grp >> 8, kb = (grp >> 6) & 3, n = grp & 63;
            union { bf16x8 v; unsigned short s[8]; } u;
#pragma unroll
            for (int i = 0; i < 8; ++i) {
                const int k = kb * 8 + i;
                u.s[i] = (k < kNB) ? bf16r(W0[(l * kNB + k) * kH + n]) : (unsigned short)0;
            }
            *reinterpret_cast<bf16x8*>(&wb0[(size_t)grp * 8]) = u.v;
        }
    } else {
#pragma unroll
        for (int q = 0; q < 4; ++q) {
            const int grp = tid * 4 + q;                 // (l*8+kb)*64 + n
            const int l = grp >> 9, kb = (grp >> 6) & 7, n = grp & 63;
            union { bf16x8 v; unsigned short s[8]; } u;
#pragma unroll
            for (int i = 0; i < 8; ++i) {
                const int k = kb * 8 + i;
                u.s[i] = bf16r(W1[(l * kH + k) * kH + n]);
            }
            *reinterpret_cast<bf16x8*>(&wb1[(size_t)grp * 8]) = u.v;
        }
    }
}

// ---------------- fused kernel: block = (z, bcol) ----------------
// Phase A: G[h,i] for b=bcol -> LDS (bf16 frag layout).
// Phase B: h2[a, bcol*64+h] for all 192 a via MFMA MLP -> wave-private LDS.
// Phase C: partial[zc][a][i] = h2[a, 64k] @ G[64k, i]  (K=64 chunk, split-K over b)
// Only ONE __syncthreads (G tile); h2 never leaves the CU.
__global__ __launch_bounds__(256) void fused_kernel(
    const float* __restrict__ feat,   // [B*N, C] layer input
    const float* __restrict__ W2,     // [H, C*C] (layer-offset)
    const float* __restrict__ b0,     // [H]
    const float* __restrict__ b1,     // [H]
    const float* __restrict__ xyz,    // [B,N,3]
    const unsigned short* __restrict__ wb0,   // layer-offset
    const unsigned short* __restrict__ wb1,   // layer-offset
    float* __restrict__ partial)      // [z*kN + bcol][kN][kC]
{
    __shared__ float fsh[kC];
    __shared__ __align__(16) unsigned short Gs[8 * kC * 8];     // [kb8][i32][8]  4KB
    __shared__ __align__(16) unsigned short h2s[4][8 * 48 * 8]; // per-wave [kb8][a48][8] 24KB
    __shared__ __align__(16) unsigned short h1b[4][1024];       // 8KB

    const int tid  = threadIdx.x;
    const int wave = tid >> 6, lane = tid & 63;
    const int g = lane >> 4, l15 = lane & 15;
    const int z = blockIdx.x / kN, bcol = blockIdx.x - z * kN;

    if (tid < kC) fsh[tid] = feat[(z * kN + bcol) * kC + tid];
    __syncthreads();

    // --- phase A: G row for b=bcol into LDS ---
#pragma unroll
    for (int p = 0; p < 8; ++p) {
        const int idx = tid + 256 * p;          // 0..2047 = h*32+i
        const int h = idx >> 5, i = idx & 31;
        const float* w = W2 + h * (kC * kC) + i * kC;
        float s = 0.f;
#pragma unroll
        for (int j = 0; j < kC; j += 4) {
            const float4 w4 = *reinterpret_cast<const float4*>(&w[j]);
            s = fmaf(w4.x, fsh[j], s);
            s = fmaf(w4.y, fsh[j + 1], s);
            s = fmaf(w4.z, fsh[j + 2], s);
            s = fmaf(w4.w, fsh[j + 3], s);
        }
        Gs[((h >> 3) * kC + i) * 8 + (h & 7)] = bf16r(s);
    }

    // --- per-lane weight frags (pre-packed, L2 broadcast) ---
    bf16x8 w0g[4], w1g[2][4];
    float b0v[4], b1v[4];
#pragma unroll
    for (int nt = 0; nt < 4; ++nt) {
        const int n = nt * 16 + l15;
        w0g[nt] = *reinterpret_cast<const bf16x8*>(&wb0[((size_t)g * kH + n) * 8]);
        b0v[nt] = b0[n];
        b1v[nt] = b1[n];
    }
#pragma unroll
    for (int ks = 0; ks < 2; ++ks)
#pragma unroll
        for (int nt = 0; nt < 4; ++nt)
            w1g[ks][nt] = *reinterpret_cast<const bf16x8*>(
                &wb1[((size_t)(ks * 4 + g) * kH + nt * 16 + l15) * 8]);

    const float bx = xyz[(z * kN + bcol) * 3 + 0];
    const float by = xyz[(z * kN + bcol) * 3 + 1];
    const float bz = xyz[(z * kN + bcol) * 3 + 2];

    unsigned short* h1w = h1b[wave];
    unsigned short* h2w = h2s[wave];

    // --- phase B: h2 for a-rows [wave*48, wave*48+48), wave-private LDS ---
#pragma unroll
    for (int t = 0; t < 3; ++t) {
        const int m0 = (wave * 3 + t) * 16;

        // A-frag: rb for edge (arow = m0+l15, bcol), k = 8g+i, in-register
        const int arow = m0 + l15;
        const float dx = xyz[(z * kN + arow) * 3 + 0] - bx;
        const float dy = xyz[(z * kN + arow) * 3 + 1] - by;
        const float dz = xyz[(z * kN + arow) * 3 + 2] - bz;
        const float d  = sqrtf(fmaf(dx, dx, fmaf(dy, dy, fmaf(dz, dz, 1e-12f))));
        const float dn = d * (19.0f / 10.0f);   // y_k = clamp(dn - k, -1, 1)
        union { bf16x8 v; unsigned short s[8]; } aU;
#pragma unroll
        for (int i = 0; i < 8; ++i) {
            const float y = fminf(1.f, fmaxf(-1.f, dn - (float)(8 * g + i)));
            aU.s[i] = bf16r(__cosf(1.57079632679f * y));
        }
        const bf16x8 aR = aU.v;   // k>=20 entries hit zero-padded W0 frags

        // GEMM-1: h1[16 a][64 h] = rb[16 a][K=32] @ W0[32][64]
#pragma unroll
        for (int nt = 0; nt < 4; ++nt) {
            f32x4 acc = {b0v[nt], b0v[nt], b0v[nt], b0v[nt]};
            acc = __builtin_amdgcn_mfma_f32_16x16x32_bf16(aR, w0g[nt], acc, 0, 0, 0);
            const int h = nt * 16 + l15;
            const int kb = h >> 3, kk = h & 7;
#pragma unroll
            for (int r = 0; r < 4; ++r)
                h1w[(kb * 16 + 4 * g + r) * 8 + kk] = bf16r(fmaxf(acc[r], 0.f));
        }
        // wave-private h1; same-wave LDS RAW ordered via lgkmcnt

        // GEMM-2: h2[16 a][64] = h1[16 a][K=64] @ W1[64][64]
        f32x4 acc2[4];
#pragma unroll
        for (int nt = 0; nt < 4; ++nt)
            acc2[nt] = (f32x4){b1v[nt], b1v[nt], b1v[nt], b1v[nt]};
#pragma unroll
        for (int ks = 0; ks < 2; ++ks) {
            const bf16x8 aH = *reinterpret_cast<const bf16x8*>(
                &h1w[((ks * 4 + g) * 16 + l15) * 8]);
#pragma unroll
            for (int nt = 0; nt < 4; ++nt)
                acc2[nt] = __builtin_amdgcn_mfma_f32_16x16x32_bf16(aH, w1g[ks][nt], acc2[nt], 0, 0, 0);
        }
#pragma unroll
        for (int nt = 0; nt < 4; ++nt) {
            const int h = nt * 16 + l15;
            const int kb = h >> 3, kk = h & 7;
#pragma unroll
            for (int r = 0; r < 4; ++r) {
                const int lt = t * 16 + 4 * g + r;   // local a row (0..47)
                h2w[(kb * 48 + lt) * 8 + kk] = bf16r(fmaxf(acc2[nt][r], 0.f));
            }
        }
    }

    __syncthreads();   // Gs ready for all waves (h2w/h1w are wave-private)

    // --- phase C: partial[zc][a][i] = h2[a][K=64] @ G[64][32] ---
    bf16x8 bG[2][2];
#pragma unroll
    for (int ks = 0; ks < 2; ++ks)
#pragma unroll
        for (int nt = 0; nt < 2; ++nt)
            bG[ks][nt] = *reinterpret_cast<const bf16x8*>(
                &Gs[((ks * 4 + g) * kC + nt * 16 + l15) * 8]);

#pragma unroll
    for (int t = 0; t < 3; ++t) {
        const int m0 = wave * 48 + t * 16;
        f32x4 acc0 = {0.f, 0.f, 0.f, 0.f}, acc1 = {0.f, 0.f, 0.f, 0.f};
#pragma unroll
        for (int ks = 0; ks < 2; ++ks) {
            const bf16x8 aF = *reinterpret_cast<const bf16x8*>(
                &h2w[((ks * 4 + g) * 48 + t * 16 + l15) * 8]);
            acc0 = __builtin_amdgcn_mfma_f32_16x16x32_bf16(aF, bG[ks][0], acc0, 0, 0, 0);
            acc1 = __builtin_amdgcn_mfma_f32_16x16x32_bf16(aF, bG[ks][1], acc1, 0, 0, 0);
        }
        float* pp = partial + ((size_t)blockIdx.x * kN + m0) * kC;
#pragma unroll
        for (int r = 0; r < 4; ++r) {
            pp[(4 * g + r) * kC + l15]      = acc0[r];
            pp[(4 * g + r) * kC + 16 + l15] = acc1[r];
        }
    }
}

// ---------------- reduce: out = (sum_b partial + b2@S) * mask / sqrt(n) ----------------
__global__ __launch_bounds__(256) void reduce_kernel(
    const float* __restrict__ partial,   // [z*kN + b][kN][kC]
    const float* __restrict__ feat,      // [B*N, C] layer input (for S)
    const float* __restrict__ b2,        // [C*C] (layer-offset)
    const float* __restrict__ mask,      // [B, N]
    float* __restrict__ dst)             // [B, N, C]
{
    __shared__ float red[8][kC];
    __shared__ float Ssh[kC];
    const int tid = threadIdx.x;
    const int z = blockIdx.x / 24;               // 24 blocks per z

    // redundant per-block S[z,j] = sum_b feat[z,b,j]
    {
        const int j = tid & 31, s = tid >> 5;
        float acc = 0.f;
        for (int b = s * 24; b < s * 24 + 24; ++b) acc += feat[(z * kN + b) * kC + j];
        red[s][j] = acc;
    }
    __syncthreads();
    if (tid < kC) {
        float v = 0.f;
#pragma unroll
        for (int q = 0; q < 8; ++q) v += red[q][tid];
        Ssh[tid] = v;
    }
    __syncthreads();

    const int o  = blockIdx.x * 256 + tid;       // < 12288
    const int ai = o - z * (kN * kC);
    const int i = ai & 31, a = ai >> 5;
    const float* p = partial + (size_t)z * kN * kN * kC + ai;
    float acc = 0.f;
#pragma unroll 8
    for (int c = 0; c < kN; ++c) acc += p[(size_t)c * kN * kC];
    float bt = 0.f;
#pragma unroll
    for (int j = 0; j < kC; ++j) bt = fmaf(b2[i * kC + j], Ssh[j], bt);
    dst[o] = (acc + bt) * kInvSqrtN * mask[z * kN + a];
}

} // namespace

extern "C" void kernel_launch(void* const* d_in, const int* in_sizes, int n_in,
                              void* d_out, int out_size, void* d_ws, size_t ws_size,
                              hipStream_t stream) {
    const float* features = (const float*)d_in[0];
    const float* xyz      = (const float*)d_in[1];
    const float* mask     = (const float*)d_in[2];
    const float* W0       = (const float*)d_in[3];
    const float* b0       = (const float*)d_in[4];
    const float* W1       = (const float*)d_in[5];
    const float* b1       = (const float*)d_in[6];
    const float* W2       = (const float*)d_in[7];
    const float* b2       = (const float*)d_in[8];
    float* out = (float*)d_out;

    // workspace layout (float offsets):
    //   wb0    :       0 ..    2048   (4096 ushort  = 2 layers x 2048)
    //   wb1    :    2048 ..    6144   (8192 ushort  = 2 layers x 4096)
    //   partial:    6144 .. 2365440   (2*192*192*32 f = 9.4MB)
    //   ftmp   : 2365440 .. 2377728
    float* ws = (float*)d_ws;
    unsigned short* wb0 = (unsigned short*)(ws);
    unsigned short* wb1 = (unsigned short*)(ws + 2048);
    float* partial = ws + 6144;
    float* ftmp    = ws + 2365440;

    init_kernel<<<2, 256, 0, stream>>>(W0, W1, wb0, wb1);

    const float* cur = features;
    for (int l = 0; l < kLayers; ++l) {
        float* dst = (l == kLayers - 1) ? out : ftmp;
        fused_kernel<<<kB * kN, 256, 0, stream>>>(
            cur, W2 + (size_t)l * kH * kC * kC,
            b0 + (size_t)l * kH, b1 + (size_t)l * kH,
            xyz, wb0 + (size_t)l * 2048, wb1 + (size_t)l * 4096,
            partial);
        reduce_kernel<<<(kB * kN * kC) / 256, 256, 0, stream>>>(
            partial, cur, b2 + (size_t)l * kC * kC, mask, dst);
        cur = dst;
    }
}